// Round 1
// baseline (81.876 us; speedup 1.0000x reference)
//
#include <hip/hip_runtime.h>
#include <hip/hip_bf16.h>

#define NUM_EXPERTS 8
#define FULL_DIM 4096
#define EXPERT_DIM 1024
#define SLICE 512
#define S0 (3*SLICE)
#define GATE_HID 128
#define P_TOK 4096
#define BATCH 4

typedef __bf16 bf16;
typedef __bf16 bf16x4 __attribute__((ext_vector_type(4)));
typedef __bf16 bf16x8 __attribute__((ext_vector_type(8)));
typedef float f32x4 __attribute__((ext_vector_type(4)));

__device__ inline void gl_lds16(const void* g, void* l) {
    __builtin_amdgcn_global_load_lds((const __attribute__((address_space(1))) void*)g,
                                     (__attribute__((address_space(3))) void*)l, 16, 0, 0);
}

// ---------------- mask + index compaction (1 block) ----------------
__global__ void k_mask(const float* __restrict__ fp, float* __restrict__ mask_out,
                       int* __restrict__ idx) {
    __shared__ int offs[256];
    int t = threadIdx.x;
    int base = t * 16;
    unsigned bits = 0;
    int c = 0;
#pragma unroll
    for (int i = 0; i < 16; i++) {
        float v = fp[base + i];
        bool m = (v >= 0.375f) && (v < 0.5f);
        mask_out[base + i] = m ? 1.0f : 0.0f;
        bits |= ((unsigned)m) << i;
        c += (int)m;
    }
    offs[t] = c;
    __syncthreads();
    if (t == 0) {
        int s = 0;
        for (int i = 0; i < 256; i++) { int cc = offs[i]; offs[i] = s; s += cc; }
    }
    __syncthreads();
    int o = offs[t];
#pragma unroll
    for (int i = 0; i < 16; i++)
        if (bits & (1u << i)) idx[o++] = base + i;
}

// ---------------- normalize pentachoron rows ----------------
__global__ void k_dirs(const float* __restrict__ penta, float* __restrict__ dirs) {
    int v = blockIdx.x, t = threadIdx.x;
    __shared__ float red[4];
    float s = 0.f;
#pragma unroll
    for (int i = 0; i < 4; i++) { float x = penta[v * 1024 + t + i * 256]; s += x * x; }
    for (int d = 32; d; d >>= 1) s += __shfl_xor(s, d);
    if ((t & 63) == 0) red[t >> 6] = s;
    __syncthreads();
    float inv = 1.0f / sqrtf(red[0] + red[1] + red[2] + red[3]);
#pragma unroll
    for (int i = 0; i < 4; i++) { int c = t + i * 256; dirs[v * 1024 + c] = penta[v * 1024 + c] * inv; }
}

// ---------------- f32 -> bf16 convert ----------------
__global__ void k_conv(const float* __restrict__ src, bf16* __restrict__ dst, int n) {
    int i = (blockIdx.x * 256 + threadIdx.x) * 4;
    if (i >= n) return;
    float4 v = *(const float4*)(src + i);
    bf16x4 b = { (bf16)v.x, (bf16)v.y, (bf16)v.z, (bf16)v.w };
    *(bf16x4*)(dst + i) = b;
}

// ---------------- gather expert slice; write f32 + bf16, zero-pad ----------------
__global__ void k_gather(const float* __restrict__ tokens, const int* __restrict__ idx,
                         int p, int M, float* __restrict__ Ff, bf16* __restrict__ Fb) {
    int t = threadIdx.x;
    int m = blockIdx.x * 2 + (t >> 7);
    int c = (t & 127) * 4;
    float4 v = { 0.f, 0.f, 0.f, 0.f };
    if (m < M) {
        int b = m / p, j = m - b * p;
        int row = idx[j];
        v = *(const float4*)(tokens + ((size_t)(b * P_TOK + row)) * FULL_DIM + S0 + c);
    }
    *(float4*)(Ff + (size_t)m * SLICE + c) = v;
    bf16x4 bv = { (bf16)v.x, (bf16)v.y, (bf16)v.z, (bf16)v.w };
    *(bf16x4*)(Fb + (size_t)m * SLICE + c) = bv;
}

// ---------------- MFMA GEMM: C[m,n] = sum_k A[m,k]*W[n,k] ----------------
// MODE 0: QKV (z-index picks weight, plain f32 write to out, guard m<M)
// MODE 1: gate layer1 (bias + exact GELU epilogue, write H)
template <int MODE>
__launch_bounds__(256)
__global__ void k_gemm(const bf16* __restrict__ A,
                       const bf16* __restrict__ W0, const bf16* __restrict__ W1,
                       const bf16* __restrict__ W2, const float* __restrict__ bias,
                       float* __restrict__ out, int M, int N, int ldout) {
    __shared__ bf16 As[128 * 32];
    __shared__ bf16 Bs[128 * 32];
    const int t = threadIdx.x;
    const int wave = t >> 6, lane = t & 63;
    const bf16* W;
    float* obase;
    if (MODE == 0) {
        int z = blockIdx.z;
        W = (z == 0) ? W0 : ((z == 1) ? W1 : W2);
        obase = out + (size_t)z * M * EXPERT_DIM;
    } else {
        W = W0;
        obase = out;
    }
    const int m0 = blockIdx.x * 128;
    const int n0 = blockIdx.y * 128;
    const int wr = wave >> 1, wc = wave & 1;

    f32x4 acc[4][4];
#pragma unroll
    for (int i = 0; i < 4; i++)
#pragma unroll
        for (int j = 0; j < 4; j++) acc[i][j] = (f32x4){0.f, 0.f, 0.f, 0.f};

    for (int k0 = 0; k0 < SLICE; k0 += 32) {
        // stage A/B tiles: 128x32 bf16 each, 2 issues of 256 threads x 16B
        const bf16* ga0 = A + (size_t)(m0 + (t >> 2)) * SLICE + k0 + (t & 3) * 8;
        const bf16* gb0 = W + (size_t)(n0 + (t >> 2)) * SLICE + k0 + (t & 3) * 8;
        // wave-uniform LDS bases (lane*16B appended by HW)
        gl_lds16(ga0,               As + wave * 512);
        gl_lds16(ga0 + 64 * SLICE,  As + 2048 + wave * 512);
        gl_lds16(gb0,               Bs + wave * 512);
        gl_lds16(gb0 + 64 * SLICE,  Bs + 2048 + wave * 512);
        __syncthreads();

        const int fr = lane & 15, fq = lane >> 4;
        bf16x8 af[4], bfr[4];
#pragma unroll
        for (int mi = 0; mi < 4; mi++)
            af[mi] = *(const bf16x8*)(As + (wr * 64 + mi * 16 + fr) * 32 + fq * 8);
#pragma unroll
        for (int ni = 0; ni < 4; ni++)
            bfr[ni] = *(const bf16x8*)(Bs + (wc * 64 + ni * 16 + fr) * 32 + fq * 8);
#pragma unroll
        for (int mi = 0; mi < 4; mi++)
#pragma unroll
            for (int ni = 0; ni < 4; ni++)
                acc[mi][ni] = __builtin_amdgcn_mfma_f32_16x16x32_bf16(af[mi], bfr[ni], acc[mi][ni], 0, 0, 0);
        __syncthreads();
    }

    const int fr = lane & 15, fq = lane >> 4;
#pragma unroll
    for (int mi = 0; mi < 4; mi++) {
#pragma unroll
        for (int ni = 0; ni < 4; ni++) {
            int col = n0 + wc * 64 + ni * 16 + fr;
            if (col >= N) continue;
#pragma unroll
            for (int r = 0; r < 4; r++) {
                int row = m0 + wr * 64 + mi * 16 + fq * 4 + r;
                if (row >= M) continue;
                float v = acc[mi][ni][r];
                if (MODE == 1) {
                    v += bias[col];
                    v = 0.5f * v * (1.0f + erff(v * 0.70710678118f));
                }
                obase[(size_t)row * ldout + col] = v;
            }
        }
    }
}

// ---------------- gate layer2 + sigmoid + feature scaling ----------------
__global__ void k_gate2(const float* __restrict__ H, const float* __restrict__ w2,
                        const float* __restrict__ b2, const float* __restrict__ alpha,
                        const float* __restrict__ Ff, bf16* __restrict__ Fs) {
    int wave = threadIdx.x >> 6, lane = threadIdx.x & 63;
    int m = blockIdx.x * 4 + wave;
    const float* h = H + (size_t)m * GATE_HID;
    float s = h[lane] * w2[lane] + h[lane + 64] * w2[lane + 64];
    for (int d = 32; d; d >>= 1) s += __shfl_xor(s, d);
    float aw = 1.0f / (1.0f + expf(-alpha[0]));
    float g = 1.0f / (1.0f + expf(-(s + b2[0])));
    float scale = g * aw + (1.0f - aw);
    const float* f = Ff + (size_t)m * SLICE;
    bf16* o = Fs + (size_t)m * SLICE;
    int c0 = lane * 8;
    float4 v0 = *(const float4*)(f + c0);
    float4 v1 = *(const float4*)(f + c0 + 4);
    bf16x8 b;
    b[0] = (bf16)(v0.x * scale); b[1] = (bf16)(v0.y * scale);
    b[2] = (bf16)(v0.z * scale); b[3] = (bf16)(v0.w * scale);
    b[4] = (bf16)(v1.x * scale); b[5] = (bf16)(v1.y * scale);
    b[6] = (bf16)(v1.z * scale); b[7] = (bf16)(v1.w * scale);
    *(bf16x8*)(o + c0) = b;
}

// ---------------- affinities: [5,M] dots of Q/K rows with dirs ----------------
__global__ void k_aff(const float* __restrict__ qkv, const float* __restrict__ dirs,
                      float* __restrict__ aff, int M) {
    int wave = threadIdx.x >> 6, lane = threadIdx.x & 63;
    int m = blockIdx.x * 4 + wave;
    if (m >= M) return;
    const float* Qrow = qkv + (size_t)m * EXPERT_DIM;
    const float* Krow = qkv + (size_t)M * EXPERT_DIM + (size_t)m * EXPERT_DIM;
    float aK[5] = {0, 0, 0, 0, 0}, aQ[5] = {0, 0, 0, 0, 0};
#pragma unroll
    for (int i = 0; i < 16; i++) {
        int c = lane + i * 64;
        float kx = Krow[c], qx = Qrow[c];
#pragma unroll
        for (int v = 0; v < 5; v++) {
            float dv = dirs[v * 1024 + c];
            aK[v] += kx * dv;
            aQ[v] += qx * dv;
        }
    }
#pragma unroll
    for (int v = 0; v < 5; v++) {
        for (int d = 32; d; d >>= 1) { aK[v] += __shfl_xor(aK[v], d); aQ[v] += __shfl_xor(aQ[v], d); }
    }
    if (lane == 0) {
#pragma unroll
        for (int v = 0; v < 5; v++) {
            aff[(size_t)v * M + m] = aK[v];
            aff[(size_t)5 * M + (size_t)v * M + m] = aQ[v];
        }
    }
}

extern "C" void kernel_launch(void* const* d_in, const int* in_sizes, int n_in,
                              void* d_out, int out_size, void* d_ws, size_t ws_size,
                              hipStream_t stream) {
    const float* tokens = (const float*)d_in[0];
    const float* fps    = (const float*)d_in[1];
    const float* alpha  = (const float*)d_in[2];
    const float* gw1    = (const float*)d_in[3];
    const float* gb1    = (const float*)d_in[4];
    const float* gw2    = (const float*)d_in[5];
    const float* gb2    = (const float*)d_in[6];
    const float* wq     = (const float*)d_in[7];
    const float* wk     = (const float*)d_in[8];
    const float* wv     = (const float*)d_in[9];
    const float* penta  = (const float*)d_in[10];
    float* out = (float*)d_out;

    int p = (out_size - P_TOK) / (3 * BATCH * EXPERT_DIM + 2 * 5 * BATCH);  // 12328
    if (p <= 0) return;
    int M = BATCH * p;
    int Mpad = (M + 127) & ~127;

    char* ws = (char*)d_ws;
    size_t off = 0;
    int*   idx  = (int*)(ws + off);   off += 16 * 1024;
    float* dirs = (float*)(ws + off); off += 32 * 1024;
    float* H    = (float*)(ws + off); off += (size_t)Mpad * GATE_HID * 4;
    float* Ff   = (float*)(ws + off); off += (size_t)Mpad * SLICE * 4;
    bf16*  Fb   = (bf16*)(ws + off);  off += (size_t)Mpad * SLICE * 2;
    bf16*  Fs   = (bf16*)(ws + off);  off += (size_t)Mpad * SLICE * 2;
    bf16*  w1b  = (bf16*)(ws + off);  off += (size_t)GATE_HID * SLICE * 2;
    bf16*  wqb  = (bf16*)(ws + off);  off += (size_t)EXPERT_DIM * SLICE * 2;
    bf16*  wkb  = (bf16*)(ws + off);  off += (size_t)EXPERT_DIM * SLICE * 2;
    bf16*  wvb  = (bf16*)(ws + off);  off += (size_t)EXPERT_DIM * SLICE * 2;
    (void)ws_size;

    float* mask_out = out + (size_t)3 * M * EXPERT_DIM + (size_t)10 * M;
    float* aff_out  = out + (size_t)3 * M * EXPERT_DIM;

    k_mask<<<1, 256, 0, stream>>>(fps, mask_out, idx);
    k_dirs<<<5, 256, 0, stream>>>(penta, dirs);
    k_conv<<<(GATE_HID * SLICE / 4 + 255) / 256, 256, 0, stream>>>(gw1, w1b, GATE_HID * SLICE);
    k_conv<<<(EXPERT_DIM * SLICE / 4 + 255) / 256, 256, 0, stream>>>(wq, wqb, EXPERT_DIM * SLICE);
    k_conv<<<(EXPERT_DIM * SLICE / 4 + 255) / 256, 256, 0, stream>>>(wk, wkb, EXPERT_DIM * SLICE);
    k_conv<<<(EXPERT_DIM * SLICE / 4 + 255) / 256, 256, 0, stream>>>(wv, wvb, EXPERT_DIM * SLICE);
    k_gather<<<Mpad / 2, 256, 0, stream>>>(tokens, idx, p, M, Ff, Fb);
    // gate layer 1: H = GELU(F @ w1^T + b1), computed over Mpad (pad rows are zeros)
    k_gemm<1><<<dim3(Mpad / 128, 1, 1), 256, 0, stream>>>(Fb, w1b, nullptr, nullptr, gb1,
                                                          H, Mpad, GATE_HID, GATE_HID);
    k_gate2<<<Mpad / 4, 256, 0, stream>>>(H, gw2, gb2, alpha, Ff, Fs);
    // QKV GEMMs
    k_gemm<0><<<dim3(Mpad / 128, EXPERT_DIM / 128, 3), 256, 0, stream>>>(Fs, wqb, wkb, wvb, nullptr,
                                                                         out, M, EXPERT_DIM, EXPERT_DIM);
    k_aff<<<(M + 3) / 4, 256, 0, stream>>>(out, dirs, aff_out, M);
}